// Round 12
// baseline (53.638 us; speedup 1.0000x reference)
//
#include <hip/hip_runtime.h>
#include <hip/hip_fp16.h>

// LogicLayer: out[b,n] = C0[n] + C1[n]*a + C2[n]*b + C3[n]*a*b,
//   a = x[b, idx_a[n]], b = x[b, idx_b[n]], C = linear combos of softmax(w[n]).
//
// R15: R14 post-mortem — DMA staging incompatible with fp16-packed tiles
// (regressed, reverted). Ledger: nt-stores won (+8), 2 independent
// blocks/CU won (+5), in-block sched dead, co-res>2 dead, DMA dead.
// Last untested combo of proven parts: TPB=1024 AT 2 blocks/CU
// (ROWS=2 -> 64 KB tile): 32 waves/CU = hardware max TLP, keeping the
// independent-block overlap. GITERS=4 -> id[] preload is only 16 VGPRs,
// issued BEFORE the stage loop so meta L2 latency hides under staging
// (R4's trick, fits 64-VGPR budget). Coefs remain in-loop (streamed).
// nt-stores + plain loads kept. If neutral: TLP conclusively dead and
// 48.6 is the structure's floor (198 MB HBM duplex + prep ~= 35 us ideal).

#define IN_N   16384
#define OUT_N  16384
#define TPB    1024
#define ROWS   2
#define GITERS (OUT_N / 4 / TPB)   // 4 neuron-quads per thread
#define SGRP   (IN_N / 4 / TPB)    // 4 column-chunks (4 cols each) per thread

typedef unsigned int u32;
typedef float f4 __attribute__((ext_vector_type(4)));

__global__ __launch_bounds__(256) void prep_kernel(const float* __restrict__ w,
                                                   const int* __restrict__ idx_a,
                                                   const int* __restrict__ idx_b,
                                                   uint2* __restrict__ pcoef,
                                                   uint4* __restrict__ pidx,
                                                   int nout) {
    int n = blockIdx.x * blockDim.x + threadIdx.x;
    if (n < nout) {
        const float4* wn4 = (const float4*)(w + (size_t)n * 16);
        float p[16];
        float4 w0 = wn4[0], w1 = wn4[1], w2 = wn4[2], w3 = wn4[3];
        p[0] = w0.x; p[1] = w0.y; p[2] = w0.z; p[3] = w0.w;
        p[4] = w1.x; p[5] = w1.y; p[6] = w1.z; p[7] = w1.w;
        p[8] = w2.x; p[9] = w2.y; p[10] = w2.z; p[11] = w2.w;
        p[12] = w3.x; p[13] = w3.y; p[14] = w3.z; p[15] = w3.w;
        float m = -1e30f;
#pragma unroll
        for (int i = 0; i < 16; ++i) m = fmaxf(m, p[i]);
        float s = 0.f;
#pragma unroll
        for (int i = 0; i < 16; ++i) { p[i] = __expf(p[i] - m); s += p[i]; }
        float inv = 1.f / s;
#pragma unroll
        for (int i = 0; i < 16; ++i) p[i] *= inv;
        // gates: 0, ab, a-ab, a, b-ab, b, a+b-2ab, a+b-ab,
        //        1-a-b+ab, 1-a-b+2ab, 1-b, 1-b+ab, 1-a, 1-a+ab, 1-ab, 1
        float c0 = p[8] + p[9] + p[10] + p[11] + p[12] + p[13] + p[14] + p[15];
        float c1 = p[2] + p[3] + p[6] + p[7] - p[8] - p[9] - p[12] - p[13];
        float c2 = p[4] + p[5] + p[6] + p[7] - p[8] - p[9] - p[10] - p[11];
        float c3 = p[1] - p[2] - p[4] - 2.f * p[6] - p[7]
                 + p[8] + 2.f * p[9] + p[11] + p[13] - p[14];
        uint2 r;
        r.x = __builtin_bit_cast(u32, __floats2half2_rn(c0, c1));
        r.y = __builtin_bit_cast(u32, __floats2half2_rn(c2, c3));
        pcoef[n] = r;
    }
    if (n < nout / 4) {
        int4 a = ((const int4*)idx_a)[n];
        int4 b = ((const int4*)idx_b)[n];
        uint4 r;
        r.x = (u32)a.x | ((u32)a.y << 16);
        r.y = (u32)a.z | ((u32)a.w << 16);
        r.z = (u32)b.x | ((u32)b.y << 16);
        r.w = (u32)b.z | ((u32)b.w << 16);
        pidx[n] = r;
    }
}

__device__ __forceinline__ float2 h2f(u32 bits) {
    return __half22float2(__builtin_bit_cast(__half2, bits));
}
__device__ __forceinline__ u32 pkh(float a, float b) {
    return __builtin_bit_cast(u32, __floats2half2_rn(a, b));
}

// one neuron, 2 rows packed in one u32 (half2). o = a*(c1+c3*b) + (c0+c2*b)
__device__ __forceinline__ float2 neuron2(u32 a, u32 b, float2 c01, float2 c23) {
    float2 af = h2f(a), bf = h2f(b);
    float2 o;
    o.x = fmaf(af.x, fmaf(c23.y, bf.x, c01.y), fmaf(c23.x, bf.x, c01.x));
    o.y = fmaf(af.y, fmaf(c23.y, bf.y, c01.y), fmaf(c23.x, bf.y, c01.x));
    return o;
}

__global__ __launch_bounds__(TPB) void logic_kernel(const float* __restrict__ x,
                                                    const uint4* __restrict__ pidx,
                                                    const uint4* __restrict__ pcoef,
                                                    float* __restrict__ out) {
    __shared__ u32 cols[IN_N];   // 64 KB: cols[i] = half2(row0,row1) of column i

    const int t = threadIdx.x;
    const int b0 = blockIdx.x * ROWS;

    // Meta preload: issue BEFORE staging so L2 latency hides under the
    // stage phase. Only id[] (16 VGPRs) — fits the 64-VGPR budget.
    uint4 id[GITERS];
#pragma unroll
    for (int k = 0; k < GITERS; ++k) id[k] = pidx[k * TPB + t];

    // Stage 2 rows, fp16 column-interleaved. PLAIN loads: x lives in L3.
    const f4* x0 = (const f4*)(x + (size_t)(b0 + 0) * IN_N);
    const f4* x1 = (const f4*)(x + (size_t)(b0 + 1) * IN_N);
#pragma unroll
    for (int g = 0; g < SGRP; ++g) {
        int c4 = g * TPB + t;
        f4 v0 = x0[c4];
        f4 v1 = x1[c4];
        uint4 q;
        q.x = pkh(v0.x, v1.x);
        q.y = pkh(v0.y, v1.y);
        q.z = pkh(v0.z, v1.z);
        q.w = pkh(v0.w, v1.w);
        *(uint4*)&cols[c4 * 4] = q;
    }
    __syncthreads();

    // Gather + compute + nt-store (writes bypass L2/L3, keep x cached).
    f4* o0p = (f4*)(out + (size_t)(b0 + 0) * OUT_N);
    f4* o1p = (f4*)(out + (size_t)(b0 + 1) * OUT_N);
#pragma unroll
    for (int k = 0; k < GITERS; ++k) {
        int q = k * TPB + t;
        uint4 cA = pcoef[2 * q + 0];   // coefs for neurons 4q..4q+1
        uint4 cB = pcoef[2 * q + 1];   // coefs for neurons 4q+2..4q+3
        u32 A0 = cols[id[k].x & 0xffff], A1 = cols[id[k].x >> 16];
        u32 A2 = cols[id[k].y & 0xffff], A3 = cols[id[k].y >> 16];
        u32 B0 = cols[id[k].z & 0xffff], B1 = cols[id[k].z >> 16];
        u32 B2 = cols[id[k].w & 0xffff], B3 = cols[id[k].w >> 16];
        float2 r0 = neuron2(A0, B0, h2f(cA.x), h2f(cA.y));
        float2 r1 = neuron2(A1, B1, h2f(cA.z), h2f(cA.w));
        float2 r2 = neuron2(A2, B2, h2f(cB.x), h2f(cB.y));
        float2 r3 = neuron2(A3, B3, h2f(cB.z), h2f(cB.w));
        f4 o0, o1;
        o0.x = r0.x; o1.x = r0.y;
        o0.y = r1.x; o1.y = r1.y;
        o0.z = r2.x; o1.z = r2.y;
        o0.w = r3.x; o1.w = r3.y;
        __builtin_nontemporal_store(o0, o0p + q);
        __builtin_nontemporal_store(o1, o1p + q);
    }
}

extern "C" void kernel_launch(void* const* d_in, const int* in_sizes, int n_in,
                              void* d_out, int out_size, void* d_ws, size_t ws_size,
                              hipStream_t stream) {
    const float* x = (const float*)d_in[0];       // (B, IN) fp32
    const float* w = (const float*)d_in[1];       // (OUT, 16) fp32
    const int* idx_a = (const int*)d_in[2];       // (OUT,) int32
    const int* idx_b = (const int*)d_in[3];       // (OUT,) int32

    const int nout = in_sizes[2];                 // 16384
    const int batch = in_sizes[0] / IN_N;         // 2048

    uint2* pcoef = (uint2*)d_ws;                              // 128 KB
    uint4* pidx  = (uint4*)((char*)d_ws + (size_t)nout * 8);  // 64 KB

    prep_kernel<<<(nout + 255) / 256, 256, 0, stream>>>(w, idx_a, idx_b,
                                                        pcoef, pidx, nout);
    logic_kernel<<<batch / ROWS, TPB, 0, stream>>>(x, pidx, (const uint4*)pcoef,
                                                   (float*)d_out);
}

// Round 13
// 49.726 us; speedup vs baseline: 1.0787x; 1.0787x over previous
//
#include <hip/hip_runtime.h>
#include <hip/hip_fp16.h>

// LogicLayer: out[b,n] = C0[n] + C1[n]*a + C2[n]*b + C3[n]*a*b,
//   a = x[b, idx_a[n]], b = x[b, idx_b[n]], C = linear combos of softmax(w[n]).
//
// R16: R15 post-mortem — TPB=1024@2blk/CU worse than TPB=512@2blk/CU; max
// TLP dead. R12 champion (48.6). Cycle walk of R12's compute loop: each
// iter is a serial chain L2-meta-load(~200cy) -> gather(~60cy) -> FMA ->
// store; nothing saturates because every wave waits at the meta load.
// Fix: software-pipeline the meta ONE iter ahead (idq/cA/cB for k+1 issued
// before computing k; k=0's meta issued before staging, hidden there).
// +12 transient VGPRs (52->~64, at budget edge — WRITE_SIZE is the spill
// canary). Everything else identical to R12: TPB=512, ROWS=2, 64 KB LDS,
// 2 blocks/CU, plain loads, nt-stores.

#define IN_N   16384
#define OUT_N  16384
#define TPB    512
#define ROWS   2
#define GITERS (OUT_N / 4 / TPB)   // 8 neuron-quads per thread
#define SGRP   (IN_N / 4 / TPB)    // 8 column-chunks (4 cols each) per thread

typedef unsigned int u32;
typedef float f4 __attribute__((ext_vector_type(4)));

__global__ __launch_bounds__(256) void prep_kernel(const float* __restrict__ w,
                                                   const int* __restrict__ idx_a,
                                                   const int* __restrict__ idx_b,
                                                   uint2* __restrict__ pcoef,
                                                   uint4* __restrict__ pidx,
                                                   int nout) {
    int n = blockIdx.x * blockDim.x + threadIdx.x;
    if (n < nout) {
        const float4* wn4 = (const float4*)(w + (size_t)n * 16);
        float p[16];
        float4 w0 = wn4[0], w1 = wn4[1], w2 = wn4[2], w3 = wn4[3];
        p[0] = w0.x; p[1] = w0.y; p[2] = w0.z; p[3] = w0.w;
        p[4] = w1.x; p[5] = w1.y; p[6] = w1.z; p[7] = w1.w;
        p[8] = w2.x; p[9] = w2.y; p[10] = w2.z; p[11] = w2.w;
        p[12] = w3.x; p[13] = w3.y; p[14] = w3.z; p[15] = w3.w;
        float m = -1e30f;
#pragma unroll
        for (int i = 0; i < 16; ++i) m = fmaxf(m, p[i]);
        float s = 0.f;
#pragma unroll
        for (int i = 0; i < 16; ++i) { p[i] = __expf(p[i] - m); s += p[i]; }
        float inv = 1.f / s;
#pragma unroll
        for (int i = 0; i < 16; ++i) p[i] *= inv;
        // gates: 0, ab, a-ab, a, b-ab, b, a+b-2ab, a+b-ab,
        //        1-a-b+ab, 1-a-b+2ab, 1-b, 1-b+ab, 1-a, 1-a+ab, 1-ab, 1
        float c0 = p[8] + p[9] + p[10] + p[11] + p[12] + p[13] + p[14] + p[15];
        float c1 = p[2] + p[3] + p[6] + p[7] - p[8] - p[9] - p[12] - p[13];
        float c2 = p[4] + p[5] + p[6] + p[7] - p[8] - p[9] - p[10] - p[11];
        float c3 = p[1] - p[2] - p[4] - 2.f * p[6] - p[7]
                 + p[8] + 2.f * p[9] + p[11] + p[13] - p[14];
        uint2 r;
        r.x = __builtin_bit_cast(u32, __floats2half2_rn(c0, c1));
        r.y = __builtin_bit_cast(u32, __floats2half2_rn(c2, c3));
        pcoef[n] = r;
    }
    if (n < nout / 4) {
        int4 a = ((const int4*)idx_a)[n];
        int4 b = ((const int4*)idx_b)[n];
        uint4 r;
        r.x = (u32)a.x | ((u32)a.y << 16);
        r.y = (u32)a.z | ((u32)a.w << 16);
        r.z = (u32)b.x | ((u32)b.y << 16);
        r.w = (u32)b.z | ((u32)b.w << 16);
        pidx[n] = r;
    }
}

__device__ __forceinline__ float2 h2f(u32 bits) {
    return __half22float2(__builtin_bit_cast(__half2, bits));
}
__device__ __forceinline__ u32 pkh(float a, float b) {
    return __builtin_bit_cast(u32, __floats2half2_rn(a, b));
}

// one neuron, 2 rows packed in one u32 (half2). o = a*(c1+c3*b) + (c0+c2*b)
__device__ __forceinline__ float2 neuron2(u32 a, u32 b, float2 c01, float2 c23) {
    float2 af = h2f(a), bf = h2f(b);
    float2 o;
    o.x = fmaf(af.x, fmaf(c23.y, bf.x, c01.y), fmaf(c23.x, bf.x, c01.x));
    o.y = fmaf(af.y, fmaf(c23.y, bf.y, c01.y), fmaf(c23.x, bf.y, c01.x));
    return o;
}

__global__ __launch_bounds__(TPB) void logic_kernel(const float* __restrict__ x,
                                                    const uint4* __restrict__ pidx,
                                                    const uint4* __restrict__ pcoef,
                                                    float* __restrict__ out) {
    __shared__ u32 cols[IN_N];   // 64 KB: cols[i] = half2(row0,row1) of column i

    const int t = threadIdx.x;
    const int b0 = blockIdx.x * ROWS;

    // Meta for iteration 0: issue BEFORE staging — L2 latency hides there.
    uint4 idq = pidx[t];
    uint4 cA  = pcoef[2 * t + 0];
    uint4 cB  = pcoef[2 * t + 1];

    // Stage 2 rows, fp16 column-interleaved. PLAIN loads: x lives in L3.
    const f4* x0 = (const f4*)(x + (size_t)(b0 + 0) * IN_N);
    const f4* x1 = (const f4*)(x + (size_t)(b0 + 1) * IN_N);
#pragma unroll
    for (int g = 0; g < SGRP; ++g) {
        int c4 = g * TPB + t;
        f4 v0 = x0[c4];
        f4 v1 = x1[c4];
        uint4 q;
        q.x = pkh(v0.x, v1.x);
        q.y = pkh(v0.y, v1.y);
        q.z = pkh(v0.z, v1.z);
        q.w = pkh(v0.w, v1.w);
        *(uint4*)&cols[c4 * 4] = q;
    }
    __syncthreads();

    // Gather + compute + nt-store, meta software-pipelined one iter ahead:
    // k+1's L2 loads issue before k's gathers, overlapping the ~200cy meta
    // latency with gather+FMA+store of the current iteration.
    f4* o0p = (f4*)(out + (size_t)(b0 + 0) * OUT_N);
    f4* o1p = (f4*)(out + (size_t)(b0 + 1) * OUT_N);
#pragma unroll
    for (int k = 0; k < GITERS; ++k) {
        const int q = k * TPB + t;
        uint4 idn = {0, 0, 0, 0}, cAn = {0, 0, 0, 0}, cBn = {0, 0, 0, 0};
        if (k + 1 < GITERS) {
            const int qn = (k + 1) * TPB + t;
            idn = pidx[qn];
            cAn = pcoef[2 * qn + 0];
            cBn = pcoef[2 * qn + 1];
        }
        u32 A0 = cols[idq.x & 0xffff], A1 = cols[idq.x >> 16];
        u32 A2 = cols[idq.y & 0xffff], A3 = cols[idq.y >> 16];
        u32 B0 = cols[idq.z & 0xffff], B1 = cols[idq.z >> 16];
        u32 B2 = cols[idq.w & 0xffff], B3 = cols[idq.w >> 16];
        float2 r0 = neuron2(A0, B0, h2f(cA.x), h2f(cA.y));
        float2 r1 = neuron2(A1, B1, h2f(cA.z), h2f(cA.w));
        float2 r2 = neuron2(A2, B2, h2f(cB.x), h2f(cB.y));
        float2 r3 = neuron2(A3, B3, h2f(cB.z), h2f(cB.w));
        f4 o0, o1;
        o0.x = r0.x; o1.x = r0.y;
        o0.y = r1.x; o1.y = r1.y;
        o0.z = r2.x; o1.z = r2.y;
        o0.w = r3.x; o1.w = r3.y;
        __builtin_nontemporal_store(o0, o0p + q);
        __builtin_nontemporal_store(o1, o1p + q);
        idq = idn; cA = cAn; cB = cBn;
    }
}

extern "C" void kernel_launch(void* const* d_in, const int* in_sizes, int n_in,
                              void* d_out, int out_size, void* d_ws, size_t ws_size,
                              hipStream_t stream) {
    const float* x = (const float*)d_in[0];       // (B, IN) fp32
    const float* w = (const float*)d_in[1];       // (OUT, 16) fp32
    const int* idx_a = (const int*)d_in[2];       // (OUT,) int32
    const int* idx_b = (const int*)d_in[3];       // (OUT,) int32

    const int nout = in_sizes[2];                 // 16384
    const int batch = in_sizes[0] / IN_N;         // 2048

    uint2* pcoef = (uint2*)d_ws;                              // 128 KB
    uint4* pidx  = (uint4*)((char*)d_ws + (size_t)nout * 8);  // 64 KB

    prep_kernel<<<(nout + 255) / 256, 256, 0, stream>>>(w, idx_a, idx_b,
                                                        pcoef, pidx, nout);
    logic_kernel<<<batch / ROWS, TPB, 0, stream>>>(x, pidx, (const uint4*)pcoef,
                                                   (float*)d_out);
}